// Round 1
// 1046.073 us; speedup vs baseline: 1.3760x; 1.3760x over previous
//
#include <hip/hip_runtime.h>
#include <hip/hip_bf16.h>
#include <math.h>

constexpr int N_NODES = 50000;
constexpr int T_STEPS = 25;
constexpr int A_DIM   = 16;
constexpr int H_DIM   = 128;
constexpr int G3      = 3 * H_DIM;   // 384
constexpr int E_EDGES = 800000;
constexpr int I_DIM   = 64;
constexpr float LN_EPS = 1e-5f;
constexpr int NT = (N_NODES + 31) / 32;   // 1563 node tiles of 32
constexpr int NT16 = N_NODES / 16;        // 3125 exact (50000 = 16*3125)

using bf16x8 = __attribute__((ext_vector_type(8))) short;
using f32x4  = __attribute__((ext_vector_type(4))) float;

static __device__ __forceinline__ float sigm(float x) { return 1.f / (1.f + __expf(-x)); }
static __device__ __forceinline__ float tanh_fast(float x) { return 2.f / (1.f + __expf(-2.f * x)) - 1.f; }
static __device__ __forceinline__ float softplus_f(float x) {
    return (x > 20.f) ? x : log1pf(__expf(x));
}
static __device__ __forceinline__ unsigned short f2bf(float f) {
    __hip_bfloat16 b = __float2bfloat16(f);   // RNE
    return *(unsigned short*)&b;
}

// ---------------- graph preprocessing ----------------

__global__ void k_zero(int* deg_out, int* deg_in, int* cursor, int* esrc) {
    for (int i = blockIdx.x * blockDim.x + threadIdx.x; i < E_EDGES; i += gridDim.x * blockDim.x) {
        esrc[i] = 0;
        if (i < N_NODES) { deg_out[i] = 0; deg_in[i] = 0; cursor[i] = 0; }
    }
}

__global__ void k_hist(const int* __restrict__ src, const int* __restrict__ dst,
                       int* __restrict__ deg_out, int* __restrict__ deg_in) {
    for (int e = blockIdx.x * blockDim.x + threadIdx.x; e < E_EDGES; e += gridDim.x * blockDim.x) {
        int s = src[e], d = dst[e];
        if (s >= 0 && s < N_NODES) atomicAdd(&deg_out[s], 1);
        if (d >= 0 && d < N_NODES) atomicAdd(&deg_in[d], 1);
    }
}

__launch_bounds__(1024)
__global__ void k_scan(const int* __restrict__ deg, int* __restrict__ offs) {
    __shared__ int wsum[16];
    __shared__ int carry;
    const int tid = threadIdx.x;
    const int lane = tid & 63, wid = tid >> 6;
    if (tid == 0) carry = 0;
    __syncthreads();
    for (int base = 0; base < N_NODES; base += 1024) {
        int i = base + tid;
        int v = (i < N_NODES) ? deg[i] : 0;
        int x = v;
        #pragma unroll
        for (int off = 1; off < 64; off <<= 1) {
            int yv = __shfl_up(x, off);
            if (lane >= off) x += yv;
        }
        if (lane == 63) wsum[wid] = x;
        __syncthreads();
        if (wid == 0 && lane < 16) {
            int s = wsum[lane];
            #pragma unroll
            for (int off = 1; off < 16; off <<= 1) {
                int yv = __shfl_up(s, off, 16);
                if (lane >= off) s += yv;
            }
            wsum[lane] = s;
        }
        __syncthreads();
        int excl = carry + (wid > 0 ? wsum[wid - 1] : 0) + x - v;
        if (i < N_NODES) offs[i] = excl;
        __syncthreads();
        if (tid == 0) carry += wsum[15];
        __syncthreads();
    }
    if (tid == 0) offs[N_NODES] = carry;
}

__global__ void k_scatter(const int* __restrict__ src, const int* __restrict__ dst,
                          const int* __restrict__ offs, int* __restrict__ cursor,
                          int* __restrict__ esrc) {
    for (int e = blockIdx.x * blockDim.x + threadIdx.x; e < E_EDGES; e += gridDim.x * blockDim.x) {
        int d = dst[e];
        if (d < 0 || d >= N_NODES) continue;
        int pos = offs[d] + atomicAdd(&cursor[d], 1);
        if (pos >= 0 && pos < E_EDGES) esrc[pos] = src[e];
    }
}

// ---------------- GRU via MFMA (unchanged — passed at 0.0078) ----------------
__launch_bounds__(512, 2)
__global__ void k_gru(const float* __restrict__ actions,
                      const float* __restrict__ hidden,
                      const float* __restrict__ W_ih,
                      const float* __restrict__ W_hh,
                      const float* __restrict__ b_ih,
                      const float* __restrict__ b_hh,
                      float* __restrict__ h_out) {
    __shared__ __align__(16) unsigned short sX[32 * 424];      // 27.1 KB
    __shared__ __align__(16) unsigned short sH[2][32 * 152];   // 19.5 KB

    const int tid  = threadIdx.x;
    const int wid  = tid >> 6;
    const int lane = tid & 63;
    const int quad = lane >> 4;
    const int l16  = lane & 15;
    const int mt   = wid & 1;
    const int g    = wid >> 1;

    int tbase[6];
    tbase[0] = (2 * g) * 16;       tbase[1] = (2 * g + 1) * 16;
    tbase[2] = (8 + 2 * g) * 16;   tbase[3] = (9 + 2 * g) * 16;
    tbase[4] = (16 + 2 * g) * 16;  tbase[5] = (17 + 2 * g) * 16;

    bf16x8 Bhh[6][4];
    #pragma unroll
    for (int ti = 0; ti < 6; ++ti) {
        const float* rowp = W_hh + (size_t)(tbase[ti] + l16) * H_DIM;
        #pragma unroll
        for (int kc = 0; kc < 4; ++kc) {
            const float* p = rowp + kc * 32 + quad * 8;
            float4 f0 = *(const float4*)p;
            float4 f1 = *(const float4*)(p + 4);
            bf16x8 v;
            v[0] = f2bf(f0.x); v[1] = f2bf(f0.y); v[2] = f2bf(f0.z); v[3] = f2bf(f0.w);
            v[4] = f2bf(f1.x); v[5] = f2bf(f1.y); v[6] = f2bf(f1.z); v[7] = f2bf(f1.w);
            Bhh[ti][kc] = v;
        }
    }
    bf16x8 Bih[6];
    #pragma unroll
    for (int ti = 0; ti < 6; ++ti) {
        bf16x8 v;
        #pragma unroll
        for (int j = 0; j < 8; ++j) v[j] = 0;
        if (quad < 2) {
            const float* p = W_ih + (size_t)(tbase[ti] + l16) * A_DIM + quad * 8;
            float4 f0 = *(const float4*)p;
            float4 f1 = *(const float4*)(p + 4);
            v[0] = f2bf(f0.x); v[1] = f2bf(f0.y); v[2] = f2bf(f0.z); v[3] = f2bf(f0.w);
            v[4] = f2bf(f1.x); v[5] = f2bf(f1.y); v[6] = f2bf(f1.z); v[7] = f2bf(f1.w);
        }
        Bih[ti] = v;
    }
    float br[2], bz[2], bin_[2], bhn[2];
    #pragma unroll
    for (int t2 = 0; t2 < 2; ++t2) {
        int j = 32 * g + 16 * t2 + l16;
        br[t2]  = b_ih[j] + b_hh[j];
        bz[t2]  = b_ih[H_DIM + j] + b_hh[H_DIM + j];
        bin_[t2] = b_ih[2 * H_DIM + j];
        bhn[t2] = b_hh[2 * H_DIM + j];
    }

    const f32x4 z4 = {0.f, 0.f, 0.f, 0.f};

    for (int tile = blockIdx.x; tile < NT; tile += gridDim.x) {
        const int base = tile * 32;
        for (int idx = tid; idx < 32 * 424; idx += 512) {
            int nl = idx / 424, p = idx - nl * 424;
            int n = base + nl;
            float f = (p < 400 && n < N_NODES) ? actions[(size_t)n * 400 + p] : 0.f;
            sX[nl * 424 + p] = f2bf(f);
        }
        for (int idx = tid; idx < 32 * H_DIM; idx += 512) {
            int nl = idx >> 7, k = idx & 127;
            int n = base + nl;
            sH[0][nl * 152 + k] = f2bf((n < N_NODES) ? hidden[(size_t)n * H_DIM + k] : 0.f);
        }
        float hp[2][4];
        #pragma unroll
        for (int t2 = 0; t2 < 2; ++t2)
            #pragma unroll
            for (int r = 0; r < 4; ++r) {
                int nl = mt * 16 + quad * 4 + r;
                int n = base + nl;
                int j = 32 * g + 16 * t2 + l16;
                hp[t2][r] = (n < N_NODES) ? hidden[(size_t)n * H_DIM + j] : 0.f;
            }
        __syncthreads();

        int cur = 0;
        for (int t = 0; t < T_STEPS; ++t) {
            bf16x8 ax;
            {
                const unsigned short* p = &sX[(mt * 16 + l16) * 424 + t * 16 + quad * 8];
                bf16x8 v = *(const bf16x8*)p;
                if (quad >= 2) {
                    #pragma unroll
                    for (int j = 0; j < 8; ++j) v[j] = 0;
                }
                ax = v;
            }
            bf16x8 ah[4];
            #pragma unroll
            for (int kc = 0; kc < 4; ++kc)
                ah[kc] = *(const bf16x8*)&sH[cur][(mt * 16 + l16) * 152 + kc * 32 + quad * 8];

            f32x4 Cr[2], Cz[2], Cin[2], Chn[2];
            #pragma unroll
            for (int t2 = 0; t2 < 2; ++t2) {
                Cr[t2]  = __builtin_amdgcn_mfma_f32_16x16x32_bf16(ax, Bih[t2],     z4, 0, 0, 0);
                Cz[t2]  = __builtin_amdgcn_mfma_f32_16x16x32_bf16(ax, Bih[2 + t2], z4, 0, 0, 0);
                Cin[t2] = __builtin_amdgcn_mfma_f32_16x16x32_bf16(ax, Bih[4 + t2], z4, 0, 0, 0);
                Chn[t2] = z4;
                #pragma unroll
                for (int kc = 0; kc < 4; ++kc) {
                    Cr[t2]  = __builtin_amdgcn_mfma_f32_16x16x32_bf16(ah[kc], Bhh[t2][kc],     Cr[t2], 0, 0, 0);
                    Cz[t2]  = __builtin_amdgcn_mfma_f32_16x16x32_bf16(ah[kc], Bhh[2 + t2][kc], Cz[t2], 0, 0, 0);
                    Chn[t2] = __builtin_amdgcn_mfma_f32_16x16x32_bf16(ah[kc], Bhh[4 + t2][kc], Chn[t2], 0, 0, 0);
                }
            }
            int nxt = cur ^ 1;
            #pragma unroll
            for (int t2 = 0; t2 < 2; ++t2) {
                #pragma unroll
                for (int r = 0; r < 4; ++r) {
                    float rg = sigm(Cr[t2][r] + br[t2]);
                    float zg = sigm(Cz[t2][r] + bz[t2]);
                    float ng = tanh_fast(Cin[t2][r] + bin_[t2] + rg * (Chn[t2][r] + bhn[t2]));
                    float h2 = ng + zg * (hp[t2][r] - ng);
                    hp[t2][r] = h2;
                    int nl = mt * 16 + quad * 4 + r;
                    int j = 32 * g + 16 * t2 + l16;
                    sH[nxt][nl * 152 + j] = f2bf(h2);
                }
            }
            cur = nxt;
            __syncthreads();
        }
        #pragma unroll
        for (int t2 = 0; t2 < 2; ++t2)
            #pragma unroll
            for (int r = 0; r < 4; ++r) {
                int nl = mt * 16 + quad * 4 + r;
                int n = base + nl;
                if (n < N_NODES) {
                    int j = 32 * g + 16 * t2 + l16;
                    h_out[(size_t)n * H_DIM + j] = hp[t2][r];
                }
            }
        __syncthreads();
    }
}

// ---------------- per-node LN stats packed: pqr[n] = {inv*ns, mu*inv*ns, ns, 0} ----------------
__global__ void k_stats(const float* __restrict__ h, const int* __restrict__ deg_out,
                        float4* __restrict__ pqr) {
    int n = blockIdx.x * (blockDim.x >> 6) + (threadIdx.x >> 6);
    int lane = threadIdx.x & 63;
    if (n >= N_NODES) return;
    float v0 = h[(size_t)n * H_DIM + lane];
    float v1 = h[(size_t)n * H_DIM + 64 + lane];
    float s = v0 + v1, qq = v0 * v0 + v1 * v1;
    #pragma unroll
    for (int m = 32; m; m >>= 1) { s += __shfl_xor(s, m); qq += __shfl_xor(qq, m); }
    float mu = s * (1.f / H_DIM);
    float var = fmaxf(qq * (1.f / H_DIM) - mu * mu, 0.f);
    float inv = rsqrtf(var + LN_EPS);
    int d = deg_out[n];
    float ns = rsqrtf((float)(d > 0 ? d : 1));
    if (lane == 0) pqr[n] = make_float4(inv * ns, mu * inv * ns, ns, 0.f);
}

// ---------------- fold Wg into the 4 heads: W_comb[r][k] = sum_c Wg[k][c]*Wh[r][c] ----------------
// b_comb[r] = sum_c Wh[r][c]*bg[c] + bh[r].  Rows: [ig_mu | ig_std | ia_mu | ia_std]
__global__ void k_comb(const float* __restrict__ Wg, const float* __restrict__ bg,
                       const float* __restrict__ Wig_mu, const float* __restrict__ big_mu,
                       const float* __restrict__ Wig_std, const float* __restrict__ big_std,
                       const float* __restrict__ Wia_mu, const float* __restrict__ bia_mu,
                       const float* __restrict__ Wia_std, const float* __restrict__ bia_std,
                       unsigned short* __restrict__ Wcomb, float* __restrict__ bcomb) {
    const int r = blockIdx.x;      // 0..255
    const int t = threadIdx.x;     // 0..127 (= k)
    const int rr = r & 63;
    const float* Wh; const float* bh;
    switch (r >> 6) {
        case 0:  Wh = Wig_mu;  bh = big_mu;  break;
        case 1:  Wh = Wig_std; bh = big_std; break;
        case 2:  Wh = Wia_mu;  bh = bia_mu;  break;
        default: Wh = Wia_std; bh = bia_std; break;
    }
    __shared__ float sWr[H_DIM];
    sWr[t] = Wh[(size_t)rr * H_DIM + t];
    __syncthreads();
    const float4* wrow = (const float4*)(Wg + (size_t)t * H_DIM);
    float acc = 0.f;
    #pragma unroll 8
    for (int c4 = 0; c4 < 32; ++c4) {
        float4 v = wrow[c4];
        acc = fmaf(v.x, sWr[4 * c4    ], acc);
        acc = fmaf(v.y, sWr[4 * c4 + 1], acc);
        acc = fmaf(v.z, sWr[4 * c4 + 2], acc);
        acc = fmaf(v.w, sWr[4 * c4 + 3], acc);
    }
    Wcomb[r * H_DIM + t] = f2bf(acc);
    if (t == 0) {
        float s = bh[rr];
        for (int c = 0; c < H_DIM; ++c) s = fmaf(bg[c], sWr[c], s);
        bcomb[r] = s;
    }
}

// ---------------- fused: edge aggregation (wave/node) + MFMA combined-head GEMM ----------------
// phase 1: y[n][j] = (g_j*(sum_e p_s*h[s][j] - sum_e q_s) + b_j*sum_e r_s)*nd  -> LDS bf16
// phase 2: out[n][r] = y[n] . W_comb[r] + b_comb[r]  (softplus on std heads)
__launch_bounds__(256)
__global__ void k_fused(const float* __restrict__ h,
                        const int* __restrict__ offs, const int* __restrict__ esrc,
                        const float4* __restrict__ pqr,
                        const float* __restrict__ ln_g, const float* __restrict__ ln_b,
                        const unsigned short* __restrict__ Wcomb,
                        const float* __restrict__ bcomb,
                        float* __restrict__ out) {
    // 16 rows x 136 ushorts (272 B rows: stride 17*16B -> ds_read_b128 only 2-way conflicts)
    __shared__ __align__(16) unsigned short yl[16][136];

    const int tid  = threadIdx.x;
    const int w    = tid >> 6;       // wave 0..3
    const int lane = tid & 63;
    const int l16  = lane & 15;
    const int quad = lane >> 4;
    const long long NI = (long long)N_NODES * I_DIM;

    // persistent B fragments: wave w owns col-tiles 4w..4w+3 (cols (4w+ct)*16+l16)
    bf16x8 B[4][4];
    float bc[4];
    #pragma unroll
    for (int ct = 0; ct < 4; ++ct) {
        int col = (w * 4 + ct) * 16 + l16;
        bc[ct] = bcomb[col];
        #pragma unroll
        for (int kc = 0; kc < 4; ++kc)
            B[ct][kc] = *(const bf16x8*)&Wcomb[col * H_DIM + kc * 32 + quad * 8];
    }
    const float2 g2 = *(const float2*)&ln_g[2 * lane];
    const float2 b2 = *(const float2*)&ln_b[2 * lane];

    for (int tile = blockIdx.x; tile < NT16; tile += gridDim.x) {
        const int base = tile * 16;
        // ---- phase 1: each wave aggregates 4 nodes; lane covers features 2*lane, 2*lane+1 ----
        #pragma unroll
        for (int i = 0; i < 4; ++i) {
            const int nl = w * 4 + i;
            const int n  = base + nl;
            const int s0 = offs[n], s1 = offs[n + 1];
            float ax = 0.f, ay = 0.f, sq = 0.f, sr = 0.f;
            for (int e0 = s0; e0 < s1; e0 += 64) {
                int sv = (e0 + lane < s1) ? esrc[e0 + lane] : 0;
                const int cnt = min(64, s1 - e0);
                for (int k = 0; k < cnt; ++k) {
                    int s = __shfl(sv, k);
                    float4 P = pqr[s];                                   // 16B broadcast
                    float2 hv = *(const float2*)&h[(size_t)s * H_DIM + 2 * lane];
                    ax = fmaf(P.x, hv.x, ax);
                    ay = fmaf(P.x, hv.y, ay);
                    sq += P.y; sr += P.z;
                }
            }
            const int d = s1 - s0;
            const float nd = rsqrtf((float)(d > 0 ? d : 1));
            float y0 = (g2.x * (ax - sq) + b2.x * sr) * nd;
            float y1 = (g2.y * (ay - sq) + b2.y * sr) * nd;
            unsigned int pk = ((unsigned int)f2bf(y1) << 16) | (unsigned int)f2bf(y0);
            *(unsigned int*)&yl[nl][2 * lane] = pk;
        }
        __syncthreads();
        // ---- phase 2: MFMA 16x128 @ 128x256 ----
        bf16x8 A[4];
        #pragma unroll
        for (int kc = 0; kc < 4; ++kc)
            A[kc] = *(const bf16x8*)&yl[l16][kc * 32 + quad * 8];
        #pragma unroll
        for (int ct = 0; ct < 4; ++ct) {
            f32x4 C = {0.f, 0.f, 0.f, 0.f};
            #pragma unroll
            for (int kc = 0; kc < 4; ++kc)
                C = __builtin_amdgcn_mfma_f32_16x16x32_bf16(A[kc], B[ct][kc], C, 0, 0, 0);
            const int col  = (w * 4 + ct) * 16 + l16;
            const int head = col >> 6;
            const int wi   = col & 63;
            const bool sp  = (col & 64) != 0;
            #pragma unroll
            for (int r_ = 0; r_ < 4; ++r_) {
                const int node = base + quad * 4 + r_;
                float v = C[r_] + bc[ct];
                if (sp) v = softplus_f(v);
                out[(long long)head * NI + (long long)node * I_DIM + wi] = v;
            }
        }
        __syncthreads();
    }
}

extern "C" void kernel_launch(void* const* d_in, const int* in_sizes, int n_in,
                              void* d_out, int out_size, void* d_ws, size_t ws_size,
                              hipStream_t stream) {
    const float* actions = (const float*)d_in[0];
    const float* hidden  = (const float*)d_in[1];
    const int*   src     = (const int*)d_in[2];
    const int*   dst     = (const int*)d_in[3];
    const float* W_ih    = (const float*)d_in[4];
    const float* W_hh    = (const float*)d_in[5];
    const float* b_ih    = (const float*)d_in[6];
    const float* b_hh    = (const float*)d_in[7];
    const float* ln_g    = (const float*)d_in[8];
    const float* ln_b    = (const float*)d_in[9];
    const float* Wg      = (const float*)d_in[10];
    const float* bg      = (const float*)d_in[11];
    const float* Wia_mu  = (const float*)d_in[12];
    const float* bia_mu  = (const float*)d_in[13];
    const float* Wia_std = (const float*)d_in[14];
    const float* bia_std = (const float*)d_in[15];
    const float* Wig_mu  = (const float*)d_in[16];
    const float* big_mu  = (const float*)d_in[17];
    const float* Wig_std = (const float*)d_in[18];
    const float* big_std = (const float*)d_in[19];
    float* out = (float*)d_out;

    // ws layout — total ~4.87 MB
    char* w = (char*)d_ws;
    const size_t SZN = 200064;               // N ints, padded to 64
    int*   deg_out = (int*)(w);
    int*   deg_in  = (int*)(w + SZN);
    int*   offs    = (int*)(w + 2 * SZN);    // N+1 ints within padded slot
    int*   cursor  = (int*)(w + 2 * SZN + 200128);
    int*   esrc    = (int*)(w + 3 * SZN + 200128);                       // E ints = 3.2 MB
    float4* pqrA   = (float4*)(w + 3 * SZN + 200128 + 3200000);          // N*16 B = 800 KB (16B aligned)
    unsigned short* Wcomb = (unsigned short*)(w + 3 * SZN + 200128 + 3200000 + 800000);  // 64 KB
    float* bcomb   = (float*)(w + 3 * SZN + 200128 + 3200000 + 800000 + 65536);          // 1 KB
    // end = 600192 + 200128 + 3200000 + 800000 + 65536 + 1024 = 4,866,880 B

    k_zero<<<2048, 256, 0, stream>>>(deg_out, deg_in, cursor, esrc);
    k_hist<<<1024, 256, 0, stream>>>(src, dst, deg_out, deg_in);
    k_scan<<<1, 1024, 0, stream>>>(deg_in, offs);
    k_scatter<<<1024, 256, 0, stream>>>(src, dst, offs, cursor, esrc);
    k_comb<<<256, 128, 0, stream>>>(Wg, bg, Wig_mu, big_mu, Wig_std, big_std,
                                    Wia_mu, bia_mu, Wia_std, bia_std, Wcomb, bcomb);

    // GRU writes f32 h directly into out section 4 (element offset 4*N*I)
    float* h_f = out + (size_t)4 * N_NODES * I_DIM;
    k_gru<<<256, 512, 0, stream>>>(actions, hidden, W_ih, W_hh, b_ih, b_hh, h_f);

    k_stats<<<(N_NODES + 3) / 4, 256, 0, stream>>>(h_f, deg_out, pqrA);

    k_fused<<<1024, 256, 0, stream>>>(h_f, offs, esrc, pqrA, ln_g, ln_b,
                                      Wcomb, bcomb, out);
}